// Round 5
// baseline (236.872 us; speedup 1.0000x reference)
//
#include <hip/hip_runtime.h>
#include <math.h>

#define BB 8
#define CC 512
#define LL 4096
#define GG 4
#define KK 3
#define EPSV 1e-5f

#define TLA 32                 // l-positions per K3a block
#define FTP 520                // ftb row stride (ushorts)
#define LCH 64                 // l-positions per K3b block
#define XPW 134                // xpad row width (floats): 128 + 3 left + 3 right clamp-pad

// ws layout (floats):
//  [0,4096) psum | [4096,8192) psq | [8192,8704) scale | [8704,9216) shift
//  [9216,17408): Wb ushort[32][512]
//  PRO: raw offsets f32 [B][L][12] ; PRW: softmax weights f32 [B][L][12]
#define WB_F32OFF 9216
#define PRO_OFF   17408
#define PRW_OFF   (PRO_OFF + BB * LL * 12)   // 410624; total ws ~3.3 MB

typedef float  f32x4_t  __attribute__((ext_vector_type(4)));
typedef __bf16 bf16x8_t __attribute__((ext_vector_type(8)));

__device__ __forceinline__ float gelu_tanh(float z) {
    float z2 = z * z;
    float a  = 1.5957691216f * fmaf(0.044715f * z2, z, z);
    return z * __builtin_amdgcn_rcpf(1.f + __expf(-a));
}

__device__ __forceinline__ ushort f32_to_bf16(float f) {
    uint u = __float_as_uint(f);
    return (ushort)((u + 0x7fffu + ((u >> 16) & 1u)) >> 16);   // RNE
}

__device__ __forceinline__ f32x4_t mfma_bf16(uint4 a, uint4 b, f32x4_t c) {
    return __builtin_amdgcn_mfma_f32_16x16x32_bf16(
        __builtin_bit_cast(bf16x8_t, a), __builtin_bit_cast(bf16x8_t, b), c, 0, 0, 0);
}

// ---------------- K1: conv + per-(c,b) partial stats ----------------
__global__ __launch_bounds__(256) void conv_stats_kernel(
    const float* __restrict__ x, const float* __restrict__ conv_w,
    const float* __restrict__ conv_b, float* __restrict__ ws)
{
    const int c = blockIdx.x;
    const int b = blockIdx.y;
    const int t = threadIdx.x;

    const float w0 = conv_w[c * 3 + 0];
    const float w1 = conv_w[c * 3 + 1];
    const float w2 = conv_w[c * 3 + 2];
    const float cb = conv_b[c];
    const float* xr = x + ((size_t)b * CC + c) * LL;

    float s = 0.f, ss = 0.f;
#pragma unroll
    for (int i = 0; i < 4; ++i) {
        const int l0 = 4 * (t + 256 * i);
        float4 q = *reinterpret_cast<const float4*>(xr + l0);
        float lf = __shfl_up(q.w, 1);
        if ((t & 63) == 0) lf = (l0 == 0) ? 0.f : xr[l0 - 1];
        float rt = __shfl_down(q.x, 1);
        if ((t & 63) == 63) rt = (l0 + 4 >= LL) ? 0.f : xr[l0 + 4];
        float y;
        y = fmaf(w0, lf,  fmaf(w1, q.x, fmaf(w2, q.y, cb))); s += y; ss = fmaf(y, y, ss);
        y = fmaf(w0, q.x, fmaf(w1, q.y, fmaf(w2, q.z, cb))); s += y; ss = fmaf(y, y, ss);
        y = fmaf(w0, q.y, fmaf(w1, q.z, fmaf(w2, q.w, cb))); s += y; ss = fmaf(y, y, ss);
        y = fmaf(w0, q.z, fmaf(w1, q.w, fmaf(w2, rt,  cb))); s += y; ss = fmaf(y, y, ss);
    }

#pragma unroll
    for (int d = 32; d > 0; d >>= 1) {
        s  += __shfl_down(s,  d, 64);
        ss += __shfl_down(ss, d, 64);
    }
    __shared__ float ls[4], lss[4];
    const int wid = t >> 6, lane = t & 63;
    if (lane == 0) { ls[wid] = s; lss[wid] = ss; }
    __syncthreads();
    if (t == 0) {
        ws[c * 8 + b]        = ls[0] + ls[1] + ls[2] + ls[3];
        ws[4096 + c * 8 + b] = lss[0] + lss[1] + lss[2] + lss[3];
    }
}

// ---------------- K2: BN finalize + W -> bf16 pre-convert ----------------
__global__ __launch_bounds__(512) void bn_finalize_kernel(
    const float* __restrict__ bn_gamma, const float* __restrict__ bn_beta,
    const float* __restrict__ off_w, const float* __restrict__ wgt_w,
    float* __restrict__ ws)
{
    const int t = threadIdx.x;
    {
        const int c = t;
        float s = 0.f, ss = 0.f;
#pragma unroll
        for (int b = 0; b < 8; ++b) {
            s  += ws[c * 8 + b];
            ss += ws[4096 + c * 8 + b];
        }
        const float inv  = 1.f / (float)(BB * LL);
        const float mean = s * inv;
        const float var  = ss * inv - mean * mean;
        const float sc   = bn_gamma[c] * rsqrtf(var + EPSV);
        ws[8192 + c] = sc;
        ws[8704 + c] = bn_beta[c] - mean * sc;
    }
    ushort* wb = reinterpret_cast<ushort*>(ws + WB_F32OFF);
    const int o  = t >> 4;
    const int k0 = (t & 15) * 32;
    uint* dst = reinterpret_cast<uint*>(wb + o * CC + k0);
    if (o < 24) {
        const float* src = (o < 12) ? (off_w + o * CC + k0) : (wgt_w + (o - 12) * CC + k0);
#pragma unroll 4
        for (int j = 0; j < 16; ++j) {
            float2 v = *reinterpret_cast<const float2*>(src + 2 * j);
            dst[j] = (uint)f32_to_bf16(v.x) | ((uint)f32_to_bf16(v.y) << 16);
        }
    } else {
#pragma unroll 4
        for (int j = 0; j < 16; ++j) dst[j] = 0u;
    }
}

// ---------------- K3a: feat (conv+BN+GELU) + MFMA projection + softmax -> coeffs ----------------
__global__ __launch_bounds__(512, 8) void proj_coeffs_kernel(
    const float* __restrict__ x,
    const float* __restrict__ conv_w, const float* __restrict__ conv_b,
    const float* __restrict__ off_b,  const float* __restrict__ wgt_b,
    float* __restrict__ ws)
{
    __shared__ ushort ftb[TLA][FTP];   // 33280 B : feat bf16, [l][c]
    __shared__ float  pr[TLA][24];     //  3072 B : raw offsets + raw logits
    // ~36.4 KB -> 4 blocks/CU

    const int t  = threadIdx.x;
    const int b  = blockIdx.y;
    const int l0 = blockIdx.x * TLA;

    // ---- Phase A: streaming conv + BN + GELU -> ftb (2-register halo, no big arrays) ----
    {
        const int ch = t;
        const float* xr = x + ((size_t)b * CC + ch) * LL + l0;
        const float w0 = conv_w[ch*3+0], w1 = conv_w[ch*3+1], w2 = conv_w[ch*3+2];
        const float sc = ws[8192 + ch];
        const float sh = fmaf(conv_b[ch], sc, ws[8704 + ch]);

        float cz = 0.f;
        float cw = (l0 == 0) ? 0.f : xr[-1];
#pragma unroll
        for (int i = 0; i < 8; ++i) {
            float4 q = *reinterpret_cast<const float4*>(xr + 4 * i);
            if (i > 0) {
                float cv = fmaf(w0, cz, fmaf(w1, cw, w2 * q.x));
                ftb[4*i-1][ch] = f32_to_bf16(gelu_tanh(fmaf(sc, cv, sh)));
            }
            float c0 = fmaf(w0, cw,  fmaf(w1, q.x, w2 * q.y));
            ftb[4*i+0][ch] = f32_to_bf16(gelu_tanh(fmaf(sc, c0, sh)));
            float c1 = fmaf(w0, q.x, fmaf(w1, q.y, w2 * q.z));
            ftb[4*i+1][ch] = f32_to_bf16(gelu_tanh(fmaf(sc, c1, sh)));
            float c2 = fmaf(w0, q.y, fmaf(w1, q.z, w2 * q.w));
            ftb[4*i+2][ch] = f32_to_bf16(gelu_tanh(fmaf(sc, c2, sh)));
            cz = q.z; cw = q.w;
        }
        float e2 = (l0 + TLA >= LL) ? 0.f : xr[TLA];
        float cv = fmaf(w0, cz, fmaf(w1, cw, w2 * e2));
        ftb[TLA-1][ch] = f32_to_bf16(gelu_tanh(fmaf(sc, cv, sh)));
    }
    __syncthreads();

    // ---- Phase C: projection via MFMA (4 waves: 2 m-subtiles x 2 n-subtiles) ----
    const int wv = t >> 6, lane = t & 63;
    if (wv < 4) {
        const int msub = wv >> 1;
        const int n    = lane & 15;
        const int kb   = (lane >> 4) * 8;
        const ushort* wrow = reinterpret_cast<const ushort*>(ws + WB_F32OFF)
                             + ((wv & 1) * 16 + n) * CC + kb;
        const ushort* arow = &ftb[msub * 16 + n][kb];
        f32x4_t acc = {0.f, 0.f, 0.f, 0.f};
#pragma unroll
        for (int s = 0; s < CC / 32; ++s) {
            uint4 av = *reinterpret_cast<const uint4*>(arow + 32 * s);
            uint4 bv = *reinterpret_cast<const uint4*>(wrow + 32 * s);
            acc = mfma_bf16(av, bv, acc);
        }
        const int o = (wv & 1) * 16 + n;
        if (o < 24) {
            float bias = (o < 12) ? off_b[o] : wgt_b[o - 12];
            const int rb = (lane >> 4) * 4;   // C/D: col=lane&15, row=(lane>>4)*4+i [m89]
#pragma unroll
            for (int i = 0; i < 4; ++i) pr[msub * 16 + rb + i][o] = acc[i] + bias;
        }
    }
    __syncthreads();

    // ---- softmax + coeff write: t < 384 -> (l, gk); global writes contiguous in t ----
    if (t < TLA * 12) {
        const int l  = t / 12;
        const int gk = t - l * 12;
        const int g  = gk / 3;
        const int k  = gk - g * 3;
        float s0 = pr[l][12 + g*3 + 0];
        float s1 = pr[l][12 + g*3 + 1];
        float s2 = pr[l][12 + g*3 + 2];
        float m  = fmaxf(s0, fmaxf(s1, s2));
        float e0 = __expf(s0 - m), e1 = __expf(s1 - m), e2 = __expf(s2 - m);
        float ek = (k == 0) ? e0 : ((k == 1) ? e1 : e2);
        float w  = ek * __builtin_amdgcn_rcpf(e0 + e1 + e2);
        const int base = ((b << 12) + l0) * 12;
        ws[PRO_OFF + base + t] = pr[l][g*3 + k];   // raw offset
        ws[PRW_OFF + base + t] = w;                // softmax weight
    }
}

// ---------------- K3b: 6-tap FIR gather along channels ----------------
// out[j] = sum_{d=0..5} W6[l,g,d] * x[clamp(j+d-3, 0, 127)]  (exact: clamp distributes)
__global__ __launch_bounds__(512, 8) void gather_kernel(
    const float* __restrict__ x, const float* __restrict__ ws,
    float* __restrict__ out)
{
    __shared__ float xpad[LCH][XPW];   // 34304 B : x[b, gbase + clamp(m-3), l0+l]
    __shared__ float W6[LCH][6];       //  1536 B
    // ~35.9 KB -> 4 blocks/CU

    const int t  = threadIdx.x;
    const int l0 = blockIdx.x * LCH;
    const int g  = blockIdx.y;
    const int b  = blockIdx.z;
    const int gbase = g << 7;
    const float* xg = x + ((size_t)b * CC + gbase) * LL;

    // ---- stage x slab (f32): 128 rows x 64 cols ----
#pragma unroll
    for (int i = 0; i < 4; ++i) {
        const int idx = i * 512 + t;         // 0..2047
        const int c   = idx >> 4;            // 0..127
        const int lq4 = idx & 15;            // 0..15 -> l = 4*lq4..
        float4 q = *reinterpret_cast<const float4*>(xg + (size_t)c * LL + l0 + 4 * lq4);
        xpad[4*lq4+0][c+3] = q.x;
        xpad[4*lq4+1][c+3] = q.y;
        xpad[4*lq4+2][c+3] = q.z;
        xpad[4*lq4+3][c+3] = q.w;
    }
    // clamp-pad columns + W6 build (one thread per l)
    if (t < LCH) {
        const int l = t;
        float xl = xg[l0 + l];                        // channel gbase+0
        float xrgt = xg[(size_t)127 * LL + l0 + l];   // channel gbase+127
        xpad[l][0] = xl;  xpad[l][1] = xl;  xpad[l][2] = xl;
        xpad[l][131] = xrgt; xpad[l][132] = xrgt; xpad[l][133] = xrgt;

        const int base = ((b << 12) + l0 + l) * 12 + g * 3;
        float w6_0 = 0.f, w6_1 = 0.f, w6_2 = 0.f, w6_3 = 0.f, w6_4 = 0.f, w6_5 = 0.f;
#pragma unroll
        for (int k = 0; k < KK; ++k) {
            float off = ws[PRO_OFF + base + k];
            float w   = ws[PRW_OFF + base + k];
            float fo  = floorf(off);
            float fr  = off - fo;
            int d = (int)fo + 3;
            d = min(max(d, 0), 4);           // safety (off in [-3,2) w.h.p.)
            float wa = w * (1.f - fr);
            float wb = w * fr;
            w6_0 += (d == 0) ? wa : 0.f;
            w6_1 += (d == 1) ? wa : 0.f;  w6_1 += (d == 0) ? wb : 0.f;
            w6_2 += (d == 2) ? wa : 0.f;  w6_2 += (d == 1) ? wb : 0.f;
            w6_3 += (d == 3) ? wa : 0.f;  w6_3 += (d == 2) ? wb : 0.f;
            w6_4 += (d == 4) ? wa : 0.f;  w6_4 += (d == 3) ? wb : 0.f;
            w6_5 += (d == 4) ? wb : 0.f;
        }
        W6[l][0] = w6_0; W6[l][1] = w6_1; W6[l][2] = w6_2;
        W6[l][3] = w6_3; W6[l][4] = w6_4; W6[l][5] = w6_5;
    }
    __syncthreads();

    // ---- gather: thread (c2 = t&127, lq = t>>7) handles 16 l ----
    const int c2 = t & 127;
    const int lq = t >> 7;
    float oacc[16];
#pragma unroll
    for (int il = 0; il < 16; ++il) {
        const int l = lq * 16 + il;
        const float* xr = &xpad[l][c2];      // taps at c2..c2+5 -> ds_read2_b32 x3
        const float* wr = &W6[l][0];
        float a = wr[0] * xr[0];
        a = fmaf(wr[1], xr[1], a);
        a = fmaf(wr[2], xr[2], a);
        a = fmaf(wr[3], xr[3], a);
        a = fmaf(wr[4], xr[4], a);
        a = fmaf(wr[5], xr[5], a);
        oacc[il] = a;
    }
    float* orow = out + ((size_t)b * CC + gbase + c2) * LL + l0 + lq * 16;
#pragma unroll
    for (int i = 0; i < 4; ++i) {
        *reinterpret_cast<float4*>(orow + 4 * i) =
            make_float4(oacc[4*i], oacc[4*i+1], oacc[4*i+2], oacc[4*i+3]);
    }
}

extern "C" void kernel_launch(void* const* d_in, const int* in_sizes, int n_in,
                              void* d_out, int out_size, void* d_ws, size_t ws_size,
                              hipStream_t stream) {
    const float* x      = (const float*)d_in[1];
    const float* conv_w = (const float*)d_in[2];
    const float* conv_b = (const float*)d_in[3];
    const float* bn_g   = (const float*)d_in[4];
    const float* bn_b   = (const float*)d_in[5];
    const float* off_w  = (const float*)d_in[6];
    const float* off_b  = (const float*)d_in[7];
    const float* wgt_w  = (const float*)d_in[8];
    const float* wgt_b  = (const float*)d_in[9];
    float* out = (float*)d_out;
    float* ws  = (float*)d_ws;

    conv_stats_kernel<<<dim3(CC, BB), 256, 0, stream>>>(x, conv_w, conv_b, ws);
    bn_finalize_kernel<<<1, 512, 0, stream>>>(bn_g, bn_b, off_w, wgt_w, ws);
    proj_coeffs_kernel<<<dim3(LL / TLA, BB), 512, 0, stream>>>(
        x, conv_w, conv_b, off_b, wgt_b, ws);
    gather_kernel<<<dim3(LL / LCH, GG, BB), 512, 0, stream>>>(x, ws, out);
}

// Round 7
// 223.396 us; speedup vs baseline: 1.0603x; 1.0603x over previous
//
#include <hip/hip_runtime.h>
#include <math.h>

#define BB 8
#define CC 512
#define LL 4096
#define GG 4
#define KK 3
#define EPSV 1e-5f

#define TL 32                  // l-positions per mega block
#define FTP 520                // ftb row stride (ushorts)
#define XGW 136                // per-group x row width (ushorts): 3 pad + 128 + 3 pad + 2 align

// ws layout (floats):
//  [0,4096) psum | [4096,8192) psq | [8192,8704) scale | [8704,9216) shift
//  [9216,17408): Wb ushort[32][512] (rows 0-11 off_w, 12-23 wgt_w, 24-31 zero)
#define WB_F32OFF 9216

typedef float  f32x4_t  __attribute__((ext_vector_type(4)));
typedef __bf16 bf16x8_t __attribute__((ext_vector_type(8)));

__device__ __forceinline__ float gelu_tanh(float z) {
    float z2 = z * z;
    float a  = 1.5957691216f * fmaf(0.044715f * z2, z, z);
    return z * __builtin_amdgcn_rcpf(1.f + __expf(-a));
}

__device__ __forceinline__ ushort f32_to_bf16(float f) {
    uint u = __float_as_uint(f);
    return (ushort)((u + 0x7fffu + ((u >> 16) & 1u)) >> 16);   // RNE
}

__device__ __forceinline__ float bf16_to_f32(ushort h) {
    return __uint_as_float((uint)h << 16);
}

__device__ __forceinline__ f32x4_t mfma_bf16(uint4 a, uint4 b, f32x4_t c) {
    return __builtin_amdgcn_mfma_f32_16x16x32_bf16(
        __builtin_bit_cast(bf16x8_t, a), __builtin_bit_cast(bf16x8_t, b), c, 0, 0, 0);
}

// ---------------- K1: conv + per-(c,b) partial stats ----------------
__global__ __launch_bounds__(256) void conv_stats_kernel(
    const float* __restrict__ x, const float* __restrict__ conv_w,
    const float* __restrict__ conv_b, float* __restrict__ ws)
{
    const int c = blockIdx.x;
    const int b = blockIdx.y;
    const int t = threadIdx.x;

    const float w0 = conv_w[c * 3 + 0];
    const float w1 = conv_w[c * 3 + 1];
    const float w2 = conv_w[c * 3 + 2];
    const float cb = conv_b[c];
    const float* xr = x + ((size_t)b * CC + c) * LL;

    float s = 0.f, ss = 0.f;
#pragma unroll
    for (int i = 0; i < 4; ++i) {
        const int l0 = 4 * (t + 256 * i);
        float4 q = *reinterpret_cast<const float4*>(xr + l0);
        float lf = __shfl_up(q.w, 1);
        if ((t & 63) == 0) lf = (l0 == 0) ? 0.f : xr[l0 - 1];
        float rt = __shfl_down(q.x, 1);
        if ((t & 63) == 63) rt = (l0 + 4 >= LL) ? 0.f : xr[l0 + 4];
        float y;
        y = fmaf(w0, lf,  fmaf(w1, q.x, fmaf(w2, q.y, cb))); s += y; ss = fmaf(y, y, ss);
        y = fmaf(w0, q.x, fmaf(w1, q.y, fmaf(w2, q.z, cb))); s += y; ss = fmaf(y, y, ss);
        y = fmaf(w0, q.y, fmaf(w1, q.z, fmaf(w2, q.w, cb))); s += y; ss = fmaf(y, y, ss);
        y = fmaf(w0, q.z, fmaf(w1, q.w, fmaf(w2, rt,  cb))); s += y; ss = fmaf(y, y, ss);
    }

#pragma unroll
    for (int d = 32; d > 0; d >>= 1) {
        s  += __shfl_down(s,  d, 64);
        ss += __shfl_down(ss, d, 64);
    }
    __shared__ float ls[4], lss[4];
    const int wid = t >> 6, lane = t & 63;
    if (lane == 0) { ls[wid] = s; lss[wid] = ss; }
    __syncthreads();
    if (t == 0) {
        ws[c * 8 + b]        = ls[0] + ls[1] + ls[2] + ls[3];
        ws[4096 + c * 8 + b] = lss[0] + lss[1] + lss[2] + lss[3];
    }
}

// ---------------- K2: BN finalize + W -> bf16 pre-convert ----------------
__global__ __launch_bounds__(512) void bn_finalize_kernel(
    const float* __restrict__ bn_gamma, const float* __restrict__ bn_beta,
    const float* __restrict__ off_w, const float* __restrict__ wgt_w,
    float* __restrict__ ws)
{
    const int t = threadIdx.x;
    {
        const int c = t;
        float s = 0.f, ss = 0.f;
#pragma unroll
        for (int b = 0; b < 8; ++b) {
            s  += ws[c * 8 + b];
            ss += ws[4096 + c * 8 + b];
        }
        const float inv  = 1.f / (float)(BB * LL);
        const float mean = s * inv;
        const float var  = ss * inv - mean * mean;
        const float sc   = bn_gamma[c] * rsqrtf(var + EPSV);
        ws[8192 + c] = sc;
        ws[8704 + c] = bn_beta[c] - mean * sc;
    }
    ushort* wb = reinterpret_cast<ushort*>(ws + WB_F32OFF);
    const int o  = t >> 4;
    const int k0 = (t & 15) * 32;
    uint* dst = reinterpret_cast<uint*>(wb + o * CC + k0);
    if (o < 24) {
        const float* src = (o < 12) ? (off_w + o * CC + k0) : (wgt_w + (o - 12) * CC + k0);
#pragma unroll 4
        for (int j = 0; j < 16; ++j) {
            float2 v = *reinterpret_cast<const float2*>(src + 2 * j);
            dst[j] = (uint)f32_to_bf16(v.x) | ((uint)f32_to_bf16(v.y) << 16);
        }
    } else {
#pragma unroll 4
        for (int j = 0; j < 16; ++j) dst[j] = 0u;
    }
}

// ---------------- K3: mega fused — feat + MFMA proj + softmax + FIR gather ----------------
__global__ __launch_bounds__(512, 4) void mega_kernel(
    const float* __restrict__ x,
    const float* __restrict__ conv_w, const float* __restrict__ conv_b,
    const float* __restrict__ off_b,  const float* __restrict__ wgt_b,
    const float* __restrict__ ws, float* __restrict__ out)
{
    __shared__ ushort xt[TL][GG][XGW];   // 34816 B : x bf16, per-group clamp-padded
    __shared__ ushort ftb[TL][FTP];      // 33280 B : feat bf16, [l][c]
    __shared__ float  pr[TL][24];        //  3072 B : raw offsets + raw logits
    __shared__ float  W6[TL][GG][6];     //  3072 B : folded 6-tap FIR weights
    // total 74240 B -> 2 blocks/CU

    const int t  = threadIdx.x;
    const int b  = blockIdx.y;
    const int bx = blockIdx.x;           // 0..127
    // XCD-chunked swizzle (128 tiles = 8 XCDs x 16 contiguous tiles); bijective
    const int ltile = ((bx & 7) << 4) | (bx >> 3);
    const int l0 = ltile * TL;

    // ---- Phase A: stream conv + BN + GELU; stage x (bf16) into xt, feat into ftb ----
    {
        const int ch = t;
        const int g  = ch >> 7;
        const int j  = ch & 127;
        const float* xr = x + ((size_t)b * CC + ch) * LL + l0;
        const float w0 = conv_w[ch*3+0], w1 = conv_w[ch*3+1], w2 = conv_w[ch*3+2];
        const float sc = ws[8192 + ch];
        const float sh = fmaf(conv_b[ch], sc, ws[8704 + ch]);

        float cz = 0.f;
        float cw = (l0 == 0) ? 0.f : xr[-1];
#pragma unroll
        for (int i = 0; i < 8; ++i) {
            float4 q = *reinterpret_cast<const float4*>(xr + 4 * i);
            xt[4*i+0][g][3+j] = f32_to_bf16(q.x);
            xt[4*i+1][g][3+j] = f32_to_bf16(q.y);
            xt[4*i+2][g][3+j] = f32_to_bf16(q.z);
            xt[4*i+3][g][3+j] = f32_to_bf16(q.w);
            if (i > 0) {
                float cv = fmaf(w0, cz, fmaf(w1, cw, w2 * q.x));
                ftb[4*i-1][ch] = f32_to_bf16(gelu_tanh(fmaf(sc, cv, sh)));
            }
            float c0 = fmaf(w0, cw,  fmaf(w1, q.x, w2 * q.y));
            ftb[4*i+0][ch] = f32_to_bf16(gelu_tanh(fmaf(sc, c0, sh)));
            float c1 = fmaf(w0, q.x, fmaf(w1, q.y, w2 * q.z));
            ftb[4*i+1][ch] = f32_to_bf16(gelu_tanh(fmaf(sc, c1, sh)));
            float c2 = fmaf(w0, q.y, fmaf(w1, q.z, w2 * q.w));
            ftb[4*i+2][ch] = f32_to_bf16(gelu_tanh(fmaf(sc, c2, sh)));
            cz = q.z; cw = q.w;
        }
        float e2 = (l0 + TL >= LL) ? 0.f : xr[TL];
        float cv = fmaf(w0, cz, fmaf(w1, cw, w2 * e2));
        ftb[TL-1][ch] = f32_to_bf16(gelu_tanh(fmaf(sc, cv, sh)));

        // group-edge clamp pads (same-thread LDS read-back; no race before barrier)
        if (j == 0) {
#pragma unroll
            for (int l = 0; l < TL; ++l) {
                ushort v = xt[l][g][3];
                xt[l][g][0] = v; xt[l][g][1] = v; xt[l][g][2] = v;
            }
        }
        if (j == 127) {
#pragma unroll
            for (int l = 0; l < TL; ++l) {
                ushort v = xt[l][g][130];
                xt[l][g][131] = v; xt[l][g][132] = v; xt[l][g][133] = v;
            }
        }
    }
    __syncthreads();

    // ---- Phase C: projection via MFMA (4 waves: 2 m-subtiles x 2 n-subtiles) ----
    const int wv = t >> 6, lane = t & 63;
    if (wv < 4) {
        const int msub = wv >> 1;
        const int n    = lane & 15;
        const int kb   = (lane >> 4) * 8;
        const ushort* wrow = reinterpret_cast<const ushort*>(ws + WB_F32OFF)
                             + ((wv & 1) * 16 + n) * CC + kb;
        const ushort* arow = &ftb[msub * 16 + n][kb];
        f32x4_t acc = {0.f, 0.f, 0.f, 0.f};
#pragma unroll
        for (int s = 0; s < CC / 32; ++s) {
            uint4 av = *reinterpret_cast<const uint4*>(arow + 32 * s);
            uint4 bv = *reinterpret_cast<const uint4*>(wrow + 32 * s);
            acc = mfma_bf16(av, bv, acc);
        }
        const int o = (wv & 1) * 16 + n;
        if (o < 24) {
            float bias = (o < 12) ? off_b[o] : wgt_b[o - 12];
            const int rb = (lane >> 4) * 4;   // C/D: col=lane&15, row=(lane>>4)*4+i [m89]
#pragma unroll
            for (int i = 0; i < 4; ++i) pr[msub * 16 + rb + i][o] = acc[i] + bias;
        }
    }
    __syncthreads();

    // ---- softmax + W6 build: one thread per (l,g) ----
    if (t < TL * GG) {
        const int l = t >> 2, g = t & 3;
        float s0 = pr[l][12 + g*3 + 0];
        float s1 = pr[l][12 + g*3 + 1];
        float s2 = pr[l][12 + g*3 + 2];
        float m  = fmaxf(s0, fmaxf(s1, s2));
        float e0 = __expf(s0 - m), e1 = __expf(s1 - m), e2 = __expf(s2 - m);
        float inv = __builtin_amdgcn_rcpf(e0 + e1 + e2);
        float wks[3] = {e0 * inv, e1 * inv, e2 * inv};
        float w6_0 = 0.f, w6_1 = 0.f, w6_2 = 0.f, w6_3 = 0.f, w6_4 = 0.f, w6_5 = 0.f;
#pragma unroll
        for (int k = 0; k < KK; ++k) {
            float off = pr[l][g*3 + k];
            float fo  = floorf(off);
            float fr  = off - fo;
            int d = (int)fo + 3;
            d = min(max(d, 0), 4);           // |off|>=3 is ~10 sigma; safety only
            float wa = wks[k] * (1.f - fr);
            float wb = wks[k] * fr;
            w6_0 += (d == 0) ? wa : 0.f;
            w6_1 += (d == 1) ? wa : 0.f;  w6_1 += (d == 0) ? wb : 0.f;
            w6_2 += (d == 2) ? wa : 0.f;  w6_2 += (d == 1) ? wb : 0.f;
            w6_3 += (d == 3) ? wa : 0.f;  w6_3 += (d == 2) ? wb : 0.f;
            w6_4 += (d == 4) ? wa : 0.f;  w6_4 += (d == 3) ? wb : 0.f;
            w6_5 += (d == 4) ? wb : 0.f;
        }
        W6[l][g][0] = w6_0; W6[l][g][1] = w6_1; W6[l][g][2] = w6_2;
        W6[l][g][3] = w6_3; W6[l][g][4] = w6_4; W6[l][g][5] = w6_5;
    }
    __syncthreads();

    // ---- Phase D: 6-tap FIR gather along channels; write full 128B rows ----
    {
        const int ch = t, g = ch >> 7, j = ch & 127;
        float* orow = out + ((size_t)b * CC + ch) * LL + l0;
#pragma unroll
        for (int h = 0; h < 4; ++h) {
            float acc[8];
#pragma unroll
            for (int u = 0; u < 8; ++u) {
                const int l = h * 8 + u;
                const ushort* xr2 = &xt[l][g][j];     // taps j..j+5 (pads absorb clamps)
                const float*  w6  = &W6[l][g][0];     // wave-uniform -> broadcast
                float a = w6[0] * bf16_to_f32(xr2[0]);
                a = fmaf(w6[1], bf16_to_f32(xr2[1]), a);
                a = fmaf(w6[2], bf16_to_f32(xr2[2]), a);
                a = fmaf(w6[3], bf16_to_f32(xr2[3]), a);
                a = fmaf(w6[4], bf16_to_f32(xr2[4]), a);
                a = fmaf(w6[5], bf16_to_f32(xr2[5]), a);
                acc[u] = a;
            }
#pragma unroll
            for (int i = 0; i < 2; ++i) {
                *reinterpret_cast<float4*>(orow + h * 8 + 4 * i) =
                    make_float4(acc[4*i], acc[4*i+1], acc[4*i+2], acc[4*i+3]);
            }
        }
    }
}

extern "C" void kernel_launch(void* const* d_in, const int* in_sizes, int n_in,
                              void* d_out, int out_size, void* d_ws, size_t ws_size,
                              hipStream_t stream) {
    const float* x      = (const float*)d_in[1];
    const float* conv_w = (const float*)d_in[2];
    const float* conv_b = (const float*)d_in[3];
    const float* bn_g   = (const float*)d_in[4];
    const float* bn_b   = (const float*)d_in[5];
    const float* off_w  = (const float*)d_in[6];
    const float* off_b  = (const float*)d_in[7];
    const float* wgt_w  = (const float*)d_in[8];
    const float* wgt_b  = (const float*)d_in[9];
    float* out = (float*)d_out;
    float* ws  = (float*)d_ws;

    conv_stats_kernel<<<dim3(CC, BB), 256, 0, stream>>>(x, conv_w, conv_b, ws);
    bn_finalize_kernel<<<1, 512, 0, stream>>>(bn_g, bn_b, off_w, wgt_w, ws);
    mega_kernel<<<dim3(LL / TL, BB), 512, 0, stream>>>(   // grid (128, 8) — FIXED
        x, conv_w, conv_b, off_b, wgt_b, ws, out);
}

// Round 8
// 203.580 us; speedup vs baseline: 1.1635x; 1.0973x over previous
//
#include <hip/hip_runtime.h>
#include <math.h>

#define BB 8
#define CC 512
#define LL 4096
#define GG 4
#define KK 3
#define EPSV 1e-5f

#define TL 32                   // l-positions per mega block
#define FTP 520                 // ftb row stride (ushorts)
#define XROWS 134               // xt rows per group: 3 pad + 128 + 3 pad
#define UNI_USHORTS (GG * XROWS * 32)   // 17152 ushorts = 34304 B (>= ftb 16640)

// ws layout (floats):
//  [0,4096) psum | [4096,8192) psq | [8192,8704) scale | [8704,9216) shift
//  [9216,17408): Wb ushort[32][512] (rows 0-11 off_w, 12-23 wgt_w, 24-31 zero)
#define WB_F32OFF 9216

typedef float  f32x4_t  __attribute__((ext_vector_type(4)));
typedef __bf16 bf16x8_t __attribute__((ext_vector_type(8)));

__device__ __forceinline__ float gelu_tanh(float z) {
    float z2 = z * z;
    float a  = 1.5957691216f * fmaf(0.044715f * z2, z, z);
    return z * __builtin_amdgcn_rcpf(1.f + __expf(-a));
}

__device__ __forceinline__ ushort f32_to_bf16(float f) {
    uint u = __float_as_uint(f);
    return (ushort)((u + 0x7fffu + ((u >> 16) & 1u)) >> 16);   // RNE
}

__device__ __forceinline__ float bf16_lo(uint u) { return __uint_as_float(u << 16); }
__device__ __forceinline__ float bf16_hi(uint u) { return __uint_as_float(u & 0xffff0000u); }

__device__ __forceinline__ uint pack2(float a, float b) {
    return (uint)f32_to_bf16(a) | ((uint)f32_to_bf16(b) << 16);
}

__device__ __forceinline__ f32x4_t mfma_bf16(uint4 a, uint4 b, f32x4_t c) {
    return __builtin_amdgcn_mfma_f32_16x16x32_bf16(
        __builtin_bit_cast(bf16x8_t, a), __builtin_bit_cast(bf16x8_t, b), c, 0, 0, 0);
}

// ---------------- K1: conv + per-(c,b) partial stats ----------------
__global__ __launch_bounds__(256) void conv_stats_kernel(
    const float* __restrict__ x, const float* __restrict__ conv_w,
    const float* __restrict__ conv_b, float* __restrict__ ws)
{
    const int c = blockIdx.x;
    const int b = blockIdx.y;
    const int t = threadIdx.x;

    const float w0 = conv_w[c * 3 + 0];
    const float w1 = conv_w[c * 3 + 1];
    const float w2 = conv_w[c * 3 + 2];
    const float cb = conv_b[c];
    const float* xr = x + ((size_t)b * CC + c) * LL;

    float s = 0.f, ss = 0.f;
#pragma unroll
    for (int i = 0; i < 4; ++i) {
        const int l0 = 4 * (t + 256 * i);
        float4 q = *reinterpret_cast<const float4*>(xr + l0);
        float lf = __shfl_up(q.w, 1);
        if ((t & 63) == 0) lf = (l0 == 0) ? 0.f : xr[l0 - 1];
        float rt = __shfl_down(q.x, 1);
        if ((t & 63) == 63) rt = (l0 + 4 >= LL) ? 0.f : xr[l0 + 4];
        float y;
        y = fmaf(w0, lf,  fmaf(w1, q.x, fmaf(w2, q.y, cb))); s += y; ss = fmaf(y, y, ss);
        y = fmaf(w0, q.x, fmaf(w1, q.y, fmaf(w2, q.z, cb))); s += y; ss = fmaf(y, y, ss);
        y = fmaf(w0, q.y, fmaf(w1, q.z, fmaf(w2, q.w, cb))); s += y; ss = fmaf(y, y, ss);
        y = fmaf(w0, q.z, fmaf(w1, q.w, fmaf(w2, rt,  cb))); s += y; ss = fmaf(y, y, ss);
    }

#pragma unroll
    for (int d = 32; d > 0; d >>= 1) {
        s  += __shfl_down(s,  d, 64);
        ss += __shfl_down(ss, d, 64);
    }
    __shared__ float ls[4], lss[4];
    const int wid = t >> 6, lane = t & 63;
    if (lane == 0) { ls[wid] = s; lss[wid] = ss; }
    __syncthreads();
    if (t == 0) {
        ws[c * 8 + b]        = ls[0] + ls[1] + ls[2] + ls[3];
        ws[4096 + c * 8 + b] = lss[0] + lss[1] + lss[2] + lss[3];
    }
}

// ---------------- K2: BN finalize + W -> bf16 pre-convert ----------------
__global__ __launch_bounds__(512) void bn_finalize_kernel(
    const float* __restrict__ bn_gamma, const float* __restrict__ bn_beta,
    const float* __restrict__ off_w, const float* __restrict__ wgt_w,
    float* __restrict__ ws)
{
    const int t = threadIdx.x;
    {
        const int c = t;
        float s = 0.f, ss = 0.f;
#pragma unroll
        for (int b = 0; b < 8; ++b) {
            s  += ws[c * 8 + b];
            ss += ws[4096 + c * 8 + b];
        }
        const float inv  = 1.f / (float)(BB * LL);
        const float mean = s * inv;
        const float var  = ss * inv - mean * mean;
        const float sc   = bn_gamma[c] * rsqrtf(var + EPSV);
        ws[8192 + c] = sc;
        ws[8704 + c] = bn_beta[c] - mean * sc;
    }
    ushort* wb = reinterpret_cast<ushort*>(ws + WB_F32OFF);
    const int o  = t >> 4;
    const int k0 = (t & 15) * 32;
    uint* dst = reinterpret_cast<uint*>(wb + o * CC + k0);
    if (o < 24) {
        const float* src = (o < 12) ? (off_w + o * CC + k0) : (wgt_w + (o - 12) * CC + k0);
#pragma unroll 4
        for (int j = 0; j < 16; ++j) {
            float2 v = *reinterpret_cast<const float2*>(src + 2 * j);
            dst[j] = pack2(v.x, v.y);
        }
    } else {
#pragma unroll 4
        for (int j = 0; j < 16; ++j) dst[j] = 0u;
    }
}

// ---------------- K3: mega fused — feat + MFMA proj + softmax + FIR gather ----------------
// LDS: uni = union{ ftb[32][520] bf16 (phase A-C) ; xt[g][134 rows][32 l] bf16 swizzled (B2-D) }
__global__ __launch_bounds__(512, 8) void mega_kernel(
    const float* __restrict__ x,
    const float* __restrict__ conv_w, const float* __restrict__ conv_b,
    const float* __restrict__ off_b,  const float* __restrict__ wgt_b,
    const float* __restrict__ ws, float* __restrict__ out)
{
    __shared__ ushort uni[UNI_USHORTS];      // 34304 B
    __shared__ float  pr[TL][24];            //  3072 B
    __shared__ float  W6[GG][6][TL];         //  3072 B  ([g][tap][l])
    // total 40448 B -> 4 blocks/CU

    const int t  = threadIdx.x;
    const int b  = blockIdx.y;
    const int bx = blockIdx.x;               // 0..127
    const int ltile = ((bx & 7) << 4) | (bx >> 3);   // XCD-chunked, bijective
    const int l0 = ltile * TL;

    const int ch = t;                        // channel for phases A/B2
    const int g  = ch >> 7;
    const int j  = ch & 127;
    const float* xr = x + ((size_t)b * CC + ch) * LL + l0;

    // ---- Phase A: stream conv + BN + GELU -> ftb(uni) ----
    {
        const float w0 = conv_w[ch*3+0], w1 = conv_w[ch*3+1], w2 = conv_w[ch*3+2];
        const float sc = ws[8192 + ch];
        const float sh = fmaf(conv_b[ch], sc, ws[8704 + ch]);

        float cz = 0.f;
        float cw = (l0 == 0) ? 0.f : xr[-1];
#pragma unroll
        for (int i = 0; i < 8; ++i) {
            float4 q = *reinterpret_cast<const float4*>(xr + 4 * i);
            if (i > 0) {
                float cv = fmaf(w0, cz, fmaf(w1, cw, w2 * q.x));
                uni[(4*i-1) * FTP + ch] = f32_to_bf16(gelu_tanh(fmaf(sc, cv, sh)));
            }
            float c0 = fmaf(w0, cw,  fmaf(w1, q.x, w2 * q.y));
            uni[(4*i+0) * FTP + ch] = f32_to_bf16(gelu_tanh(fmaf(sc, c0, sh)));
            float c1 = fmaf(w0, q.x, fmaf(w1, q.y, w2 * q.z));
            uni[(4*i+1) * FTP + ch] = f32_to_bf16(gelu_tanh(fmaf(sc, c1, sh)));
            float c2 = fmaf(w0, q.y, fmaf(w1, q.z, w2 * q.w));
            uni[(4*i+2) * FTP + ch] = f32_to_bf16(gelu_tanh(fmaf(sc, c2, sh)));
            cz = q.z; cw = q.w;
        }
        float e2 = (l0 + TL >= LL) ? 0.f : xr[TL];
        float cv = fmaf(w0, cz, fmaf(w1, cw, w2 * e2));
        uni[(TL-1) * FTP + ch] = f32_to_bf16(gelu_tanh(fmaf(sc, cv, sh)));
    }
    __syncthreads();

    // ---- Phase C: projection via MFMA (waves 0-3; 2 m-subtiles x 2 n-subtiles) ----
    const int wv = t >> 6, lane = t & 63;
    if (wv < 4) {
        const int msub = wv >> 1;
        const int n    = lane & 15;
        const int kb   = (lane >> 4) * 8;
        const ushort* wrow = reinterpret_cast<const ushort*>(ws + WB_F32OFF)
                             + ((wv & 1) * 16 + n) * CC + kb;
        const ushort* arow = &uni[(msub * 16 + n) * FTP + kb];
        f32x4_t acc = {0.f, 0.f, 0.f, 0.f};
#pragma unroll
        for (int s = 0; s < CC / 32; ++s) {
            uint4 av = *reinterpret_cast<const uint4*>(arow + 32 * s);
            uint4 bv = *reinterpret_cast<const uint4*>(wrow + 32 * s);
            acc = mfma_bf16(av, bv, acc);
        }
        const int o = (wv & 1) * 16 + n;
        if (o < 24) {
            float bias = (o < 12) ? off_b[o] : wgt_b[o - 12];
            const int rb = (lane >> 4) * 4;   // C/D: col=lane&15, row=(lane>>4)*4+i [m89]
#pragma unroll
            for (int i = 0; i < 4; ++i) pr[msub * 16 + rb + i][o] = acc[i] + bias;
        }
    }
    __syncthreads();   // pr ready; ftb dead beyond this point

    // ---- Phase B2: re-stage x (L2-hot) -> xt(uni, swizzled) ; t<128 also softmax+W6 ----
    {
        // xt ushort index: row_full = g*134 + row, idx = row_full*32 + (l ^ ((row_full&3)<<3))
        const int rf  = g * XROWS + 3 + j;
        const int key = rf & 3;
        uint4* ubase = reinterpret_cast<uint4*>(uni);
        uint4 chunks[4];
#pragma unroll
        for (int w = 0; w < 4; ++w) {
            float4 qa = *reinterpret_cast<const float4*>(xr + 8 * w);
            float4 qb = *reinterpret_cast<const float4*>(xr + 8 * w + 4);
            chunks[w] = make_uint4(pack2(qa.x, qa.y), pack2(qa.z, qa.w),
                                   pack2(qb.x, qb.y), pack2(qb.z, qb.w));
            ubase[rf * 4 + (w ^ key)] = chunks[w];
        }
        if (j == 0) {       // left clamp pads: rows rf-3..rf-1 replicate channel 0
#pragma unroll
            for (int p = 0; p < 3; ++p) {
                const int r2 = g * XROWS + p, k2 = r2 & 3;
#pragma unroll
                for (int w = 0; w < 4; ++w) ubase[r2 * 4 + (w ^ k2)] = chunks[w];
            }
        }
        if (j == 127) {     // right clamp pads
#pragma unroll
            for (int p = 0; p < 3; ++p) {
                const int r2 = g * XROWS + 131 + p, k2 = r2 & 3;
#pragma unroll
                for (int w = 0; w < 4; ++w) ubase[r2 * 4 + (w ^ k2)] = chunks[w];
            }
        }
    }
    if (t < TL * GG) {      // softmax + FIR weight build, one thread per (l,g)
        const int l = t >> 2, gg = t & 3;
        float s0 = pr[l][12 + gg*3 + 0];
        float s1 = pr[l][12 + gg*3 + 1];
        float s2 = pr[l][12 + gg*3 + 2];
        float m  = fmaxf(s0, fmaxf(s1, s2));
        float e0 = __expf(s0 - m), e1 = __expf(s1 - m), e2 = __expf(s2 - m);
        float inv = __builtin_amdgcn_rcpf(e0 + e1 + e2);
        float wks[3] = {e0 * inv, e1 * inv, e2 * inv};
        float w6v[6] = {0.f, 0.f, 0.f, 0.f, 0.f, 0.f};
#pragma unroll
        for (int k = 0; k < KK; ++k) {
            float off = pr[l][gg*3 + k];
            float fo  = floorf(off);
            float fr  = off - fo;
            int d = (int)fo + 3;
            d = min(max(d, 0), 4);           // |off|>=3 is ~10 sigma; safety only
            float wa = wks[k] * (1.f - fr);
            float wb = wks[k] * fr;
#pragma unroll
            for (int q = 0; q < 5; ++q) w6v[q] += (d == q) ? wa : 0.f;
#pragma unroll
            for (int q = 1; q < 6; ++q) w6v[q] += (d == q - 1) ? wb : 0.f;
        }
#pragma unroll
        for (int q = 0; q < 6; ++q) W6[gg][q][l] = w6v[q];
    }
    __syncthreads();

    // ---- Phase D: 6-tap FIR; thread -> (row=t>>3 + 64i, l-quad=t&7); 128B-line writes ----
    {
        const int rbase = t >> 3;           // 0..63
        const int l     = (t & 7) * 4;
        float4 w6c[6];
#pragma unroll
        for (int i = 0; i < 8; ++i) {
            const int r  = rbase + 64 * i;
            const int gi = r >> 7;
            const int ji = r & 127;
            if ((i & 1) == 0) {             // refresh W6 cache on group change
#pragma unroll
                for (int d = 0; d < 6; ++d)
                    w6c[d] = *reinterpret_cast<const float4*>(&W6[gi][d][l]);
            }
            float ax = 0.f, ay = 0.f, az = 0.f, aw = 0.f;
#pragma unroll
            for (int d = 0; d < 6; ++d) {
                const int rf2 = gi * XROWS + ji + d;       // tap row (pads absorb clamp)
                const int idx = rf2 * 32 + (l ^ ((rf2 & 3) << 3));
                uint2 u = *reinterpret_cast<const uint2*>(&uni[idx]);   // ds_read_b64
                ax = fmaf(w6c[d].x, bf16_lo(u.x), ax);
                ay = fmaf(w6c[d].y, bf16_hi(u.x), ay);
                az = fmaf(w6c[d].z, bf16_lo(u.y), az);
                aw = fmaf(w6c[d].w, bf16_hi(u.y), aw);
            }
            *reinterpret_cast<float4*>(out + ((size_t)b * CC + r) * LL + l0 + l) =
                make_float4(ax, ay, az, aw);
        }
    }
}

extern "C" void kernel_launch(void* const* d_in, const int* in_sizes, int n_in,
                              void* d_out, int out_size, void* d_ws, size_t ws_size,
                              hipStream_t stream) {
    const float* x      = (const float*)d_in[1];
    const float* conv_w = (const float*)d_in[2];
    const float* conv_b = (const float*)d_in[3];
    const float* bn_g   = (const float*)d_in[4];
    const float* bn_b   = (const float*)d_in[5];
    const float* off_w  = (const float*)d_in[6];
    const float* off_b  = (const float*)d_in[7];
    const float* wgt_w  = (const float*)d_in[8];
    const float* wgt_b  = (const float*)d_in[9];
    float* out = (float*)d_out;
    float* ws  = (float*)d_ws;

    conv_stats_kernel<<<dim3(CC, BB), 256, 0, stream>>>(x, conv_w, conv_b, ws);
    bn_finalize_kernel<<<1, 512, 0, stream>>>(bn_g, bn_b, off_w, wgt_w, ws);
    mega_kernel<<<dim3(LL / TL, BB), 512, 0, stream>>>(
        x, conv_w, conv_b, off_b, wgt_b, ws, out);
}